// Round 3
// baseline (22519.550 us; speedup 1.0000x reference)
//
#include <hip/hip_runtime.h>

#define T_STEPS 512
#define BATCH   64
#define DIM     1024
#define HID     1024
#define G4      4096   // 4*HID
#define KTOT    2048   // DIM + HID (combined gate-K)
#define CPB     16     // gate columns per block (4 h-cols x 4 gates)
#define KCH     16     // k per chunk
#define NCH     16     // chunks per wave (16*16 = 256 k per wave)

// ---------------------------------------------------------------------------
// pack_w: one-time reorder of W_ih/W_hh into per-block-contiguous rows:
//   Wp[bid][kg][c] (c=0..15), kg in [0,2048): kg<1024 -> W_ih, else W_hh.
//   n(c) = (c>>2)*HID + bid*4 + (c&3)   (c = gate*4 + jj)
// This makes the 16 w-values needed at a given k one s_load_dwordx16.
// ---------------------------------------------------------------------------
__global__ __launch_bounds__(256) void pack_w(
    const float* __restrict__ Wih, const float* __restrict__ Whh,
    float* __restrict__ Wp)
{
    const int bid = blockIdx.x;   // 0..255
    const int tid = threadIdx.x;  // 0..255
    for (int c = 0; c < CPB; ++c) {
        const int n = (c >> 2) * HID + bid * 4 + (c & 3);
#pragma unroll
        for (int r = 0; r < 8; ++r) {
            const int kg = r * 256 + tid;       // coalesced read along k
            const float v = (kg < DIM) ? Wih[(size_t)n * DIM + kg]
                                       : Whh[(size_t)n * HID + (kg - DIM)];
            Wp[((size_t)bid * KTOT + kg) * CPB + c] = v;
        }
    }
}

// ---------------------------------------------------------------------------
// Fused per-step LSTM, v3: W streamed through SGPRs (scalar loads), LDS used
// only for h/x staging + reduction. lane = b (64 lanes = 64 batch rows),
// acc[16] = all 16 gate cols, K split 8-way across waves (waves 0..3: x half,
// 4..7: h half; 256 k each, 16 chunks of 16 k). Wave-private staging slice
// -> zero barriers in the main loop. Per 4 k: 1 ds_read_b128 (h) + 4
// s_load_dwordx16 (w) + 64 v_fmac(vacc, s_w, v_h).
// LDS read volume drops ~4x vs v2 (was the measured bottleneck).
// ---------------------------------------------------------------------------
template <bool PACKED>
__global__ __launch_bounds__(512) void lstm_step(
    const float* __restrict__ x,      // [B][DIM]
    const float* __restrict__ hprev,  // [B][HID]
    const float* __restrict__ cprev,  // [B][HID]
    const float* __restrict__ Wih,    // [G4][DIM]   (used when !PACKED)
    const float* __restrict__ Whh,    // [G4][HID]   (used when !PACKED)
    const float* __restrict__ Wp,     // [256][KTOT][CPB] (used when PACKED)
    const float* __restrict__ bih,    // [G4]
    const float* __restrict__ bhh,    // [G4]
    float* __restrict__ cnext,        // [B][HID]
    float* __restrict__ hout,         // [B][HID]
    float* __restrict__ tail)         // last step: hT ++ cT
{
    // [wv][b][k] stride 20 floats: 80B rows (b128-aligned); read slot
    // (5*gl + kblk) % 8 spreads 64 lanes over all 8 16B-slots (optimal).
    __shared__ float h_s[8][64][20];     // 40960 B
    __shared__ float gates_s[64][20];    //  5120 B
    // partial buffer aliases h_s (barrier-separated): [wv][b][c] stride 20
    float* part_s = &h_s[0][0][0];       // needs 8*64*20 = 10240 floats, exact

    const int bid = blockIdx.x;          // 0..255
    const int tid = threadIdx.x;         // 0..511
    const int j0  = bid * 4;
    const int wvu = __builtin_amdgcn_readfirstlane(tid >> 6);  // wave id, uniform
    const int gl  = tid & 63;            // lane = batch row b

    const float* __restrict__ src = (wvu < 4) ? x : hprev;   // both [64][1024]
    const int kloc0  = (wvu & 3) * 256;  // k base within src row
    const int kglob0 = wvu * 256;        // k base in combined gate-K (0..2047)

    float acc[16] = {};
    float4 hv[4];

    // prefetch chunk 0 (global -> regs)
#pragma unroll
    for (int r = 0; r < 4; ++r) {
        const int fidx = r * 64 + gl;          // 0..255 float4s (64b x 4 quads)
        const int b    = fidx >> 2;
        const int k4   = (fidx & 3) * 4;
        hv[r] = *(const float4*)(src + b * DIM + kloc0 + k4);
    }

    for (int ci = 0; ci < NCH; ++ci) {
        // regs -> wave-private LDS slice (same-wave DS ops are in-order)
#pragma unroll
        for (int r = 0; r < 4; ++r) {
            const int fidx = r * 64 + gl;
            const int b    = fidx >> 2;
            const int k4   = (fidx & 3) * 4;
            *(float4*)&h_s[wvu][b][k4] = hv[r];
        }
        // prefetch next chunk (flies under the FMAs)
        if (ci < NCH - 1) {
            const int kb = kloc0 + (ci + 1) * KCH;
#pragma unroll
            for (int r = 0; r < 4; ++r) {
                const int fidx = r * 64 + gl;
                const int b    = fidx >> 2;
                const int k4   = (fidx & 3) * 4;
                hv[r] = *(const float4*)(src + b * DIM + kb + k4);
            }
        }
        // compute: 16 k, acc[16] += w[k][c] * h[b][k]
        const int kg0 = kglob0 + ci * KCH;
#pragma unroll
        for (int k4 = 0; k4 < KCH; k4 += 4) {
            const float4 h4 = *(const float4*)&h_s[wvu][gl][k4];
            const float hr[4] = {h4.x, h4.y, h4.z, h4.w};
#pragma unroll
            for (int kk = 0; kk < 4; ++kk) {
                const int kg = kg0 + k4 + kk;   // uniform
                if (PACKED) {
                    const float* __restrict__ wrow =
                        Wp + ((size_t)bid * KTOT + kg) * CPB;  // uniform addr
#pragma unroll
                    for (int c = 0; c < CPB; ++c)
                        acc[c] = fmaf(wrow[c], hr[kk], acc[c]);
                } else {
#pragma unroll
                    for (int c = 0; c < CPB; ++c) {
                        const int n = (c >> 2) * HID + j0 + (c & 3);
                        const float w = (kg < DIM)
                            ? Wih[(size_t)n * DIM + kg]
                            : Whh[(size_t)n * HID + (kg - DIM)];
                        acc[c] = fmaf(w, hr[kk], acc[c]);
                    }
                }
            }
        }
    }

    // --- reduce 8 K-split partials (part_s aliases h_s: barrier first) ---
    __syncthreads();
#pragma unroll
    for (int q = 0; q < 4; ++q) {
        float4 v; v.x = acc[q*4+0]; v.y = acc[q*4+1]; v.z = acc[q*4+2]; v.w = acc[q*4+3];
        *(float4*)&part_s[((wvu * 64 + gl) * 20) + q * 4] = v;
    }
    __syncthreads();
    if (tid < 256) {
        const int b = tid >> 2;       // 0..63
        const int q = tid & 3;        // col quad
        float4 s = {0.f, 0.f, 0.f, 0.f};
#pragma unroll
        for (int wv = 0; wv < 8; ++wv) {
            const float4 p = *(const float4*)&part_s[((wv * 64 + b) * 20) + q * 4];
            s.x += p.x; s.y += p.y; s.z += p.z; s.w += p.w;
        }
        *(float4*)&gates_s[b][q * 4] = s;
    }
    __syncthreads();

    // --- elementwise LSTM cell update: thread -> (b, jj) ---
    if (tid < 256) {
        const int b  = tid >> 2;
        const int jj = tid & 3;
        const int j  = j0 + jj;
        const float pre_i = gates_s[b][0  + jj] + bih[0 * HID + j] + bhh[0 * HID + j];
        const float pre_f = gates_s[b][4  + jj] + bih[1 * HID + j] + bhh[1 * HID + j];
        const float pre_g = gates_s[b][8  + jj] + bih[2 * HID + j] + bhh[2 * HID + j];
        const float pre_o = gates_s[b][12 + jj] + bih[3 * HID + j] + bhh[3 * HID + j];
        const float ig = 1.0f / (1.0f + __expf(-pre_i));
        const float fg = 1.0f / (1.0f + __expf(-pre_f));
        const float gg = tanhf(pre_g);
        const float og = 1.0f / (1.0f + __expf(-pre_o));
        const float cp = cprev[b * HID + j];
        const float cn = fg * cp + ig * gg;
        const float hn = og * tanhf(cn);
        cnext[b * HID + j] = cn;
        hout[b * HID + j]  = hn;
        if (tail) {
            tail[b * HID + j] = hn;                           // h_T
            tail[(size_t)BATCH * HID + b * HID + j] = cn;     // c_T
        }
    }
}

// ---------------------------------------------------------------------------
extern "C" void kernel_launch(void* const* d_in, const int* in_sizes, int n_in,
                              void* d_out, int out_size, void* d_ws, size_t ws_size,
                              hipStream_t stream) {
    const float* inputs = (const float*)d_in[0];  // [T][B][DIM]
    const float* h0     = (const float*)d_in[1];
    const float* c0     = (const float*)d_in[2];
    const float* W_ih   = (const float*)d_in[3];
    const float* W_hh   = (const float*)d_in[4];
    const float* b_ih   = (const float*)d_in[5];
    const float* b_hh   = (const float*)d_in[6];
    float* out = (float*)d_out;

    const size_t wp_floats = (size_t)256 * KTOT * CPB;         // 8.39M = 32 MB
    const size_t need      = (wp_floats + (size_t)BATCH * HID) * sizeof(float);
    const bool packed      = ws_size >= need;

    float* Wp   = (float*)d_ws;
    float* cbuf = packed ? Wp + wp_floats : (float*)d_ws;

    if (packed)
        pack_w<<<dim3(256), dim3(256), 0, stream>>>(W_ih, W_hh, Wp);

    for (int t = 0; t < T_STEPS; ++t) {
        const float* x  = inputs + (size_t)t * BATCH * DIM;
        const float* hp = (t == 0) ? h0 : out + (size_t)(t - 1) * BATCH * HID;
        const float* cp = (t == 0) ? c0 : cbuf;
        float* ho   = out + (size_t)t * BATCH * HID;
        float* tail = (t == T_STEPS - 1) ? out + (size_t)T_STEPS * BATCH * HID
                                         : nullptr;
        if (packed)
            lstm_step<true><<<dim3(256), dim3(512), 0, stream>>>(
                x, hp, cp, W_ih, W_hh, Wp, b_ih, b_hh, cbuf, ho, tail);
        else
            lstm_step<false><<<dim3(256), dim3(512), 0, stream>>>(
                x, hp, cp, W_ih, W_hh, Wp, b_ih, b_hh, cbuf, ho, tail);
    }
}

// Round 4
// 7612.563 us; speedup vs baseline: 2.9582x; 2.9582x over previous
//
#include <hip/hip_runtime.h>

#define T_STEPS 512
#define BATCH   64
#define DIM     1024
#define HID     1024
#define G4      4096   // 4*HID
#define KTOT    2048   // DIM + HID
#define NKS     64     // K-steps of 32 (2048/32)

typedef __attribute__((ext_vector_type(8))) short s8v;    // 8 bf16 = 4 VGPR
typedef __attribute__((ext_vector_type(4))) float f32x4;

__device__ __forceinline__ unsigned short f2bf(float f) {
    unsigned int u = __float_as_uint(f);
    u = u + 0x7FFFu + ((u >> 16) & 1u);       // RNE; values bounded, no inf/nan
    return (unsigned short)(u >> 16);
}
__device__ __forceinline__ float bf2f(unsigned short s) {
    return __uint_as_float(((unsigned int)s) << 16);
}

// ---------------------------------------------------------------------------
// Fragment convention (A and B share it -> result exact for any HW k-order):
//   frag for (tile, kstep): lane l, elem e
//     A: row  = l&15,  k = kstep*32 + (l>>4)*8 + e
//     B: col  = l&15,  k = kstep*32 + (l>>4)*8 + e
//   D (m89-verified): col = l&15, row = (l>>4)*4 + reg
// Packed planes (hi/lo separate), all fragment-major so kernel loads are
// contiguous 16B per lane:
//   xP[t][ks<32][m][l][e]   : idx = (((t*32+ks)*4+m)*64+l)*8+e
//   wP[bid][ks<64][l][e]    : idx = ((bid*64+ks)*64+l)*8+e
//   hP[par][ks<32][m][l][e] : idx = (((par*32+ks)*4+m)*64+l)*8+e
// ---------------------------------------------------------------------------

__global__ __launch_bounds__(256) void pack_x(
    const float* __restrict__ inp, unsigned short* __restrict__ hi,
    unsigned short* __restrict__ lo)
{
    const size_t tau = (size_t)blockIdx.x * 256 + threadIdx.x;  // < 4,194,304
    const int l  = (int)(tau & 63);
    const int m  = (int)((tau >> 6) & 3);
    const int ks = (int)((tau >> 8) & 31);
    const int t  = (int)(tau >> 13);
    const int b  = 16 * m + (l & 15);
    const int k  = ks * 32 + (l >> 4) * 8;
    const float* src = inp + ((size_t)t * BATCH + b) * DIM + k;
    float f[8];
    *(float4*)&f[0] = *(const float4*)src;
    *(float4*)&f[4] = *(const float4*)(src + 4);
    s8v vh, vl;
#pragma unroll
    for (int e = 0; e < 8; ++e) {
        const unsigned short h8 = f2bf(f[e]);
        vh[e] = (short)h8;
        vl[e] = (short)f2bf(f[e] - bf2f(h8));
    }
    *(s8v*)(hi + tau * 8) = vh;
    *(s8v*)(lo + tau * 8) = vl;
}

__global__ __launch_bounds__(256) void pack_w(
    const float* __restrict__ Wih, const float* __restrict__ Whh,
    unsigned short* __restrict__ hi, unsigned short* __restrict__ lo)
{
    const size_t tau = (size_t)blockIdx.x * 256 + threadIdx.x;  // < 1,048,576
    const int l   = (int)(tau & 63);
    const int ks  = (int)((tau >> 6) & 63);
    const int bid = (int)(tau >> 12);
    const int c   = l & 15;
    const int n   = (c >> 2) * HID + bid * 4 + (c & 3);
    const int k   = ks * 32 + (l >> 4) * 8;
    const float* src = (k < DIM) ? (Wih + (size_t)n * DIM + k)
                                 : (Whh + (size_t)n * HID + (k - DIM));
    float f[8];
    *(float4*)&f[0] = *(const float4*)src;
    *(float4*)&f[4] = *(const float4*)(src + 4);
    s8v vh, vl;
#pragma unroll
    for (int e = 0; e < 8; ++e) {
        const unsigned short h8 = f2bf(f[e]);
        vh[e] = (short)h8;
        vl[e] = (short)f2bf(f[e] - bf2f(h8));
    }
    *(s8v*)(hi + tau * 8) = vh;
    *(s8v*)(lo + tau * 8) = vl;
}

__global__ __launch_bounds__(256) void pack_h0(
    const float* __restrict__ h0, unsigned short* __restrict__ hi,
    unsigned short* __restrict__ lo)
{
    const size_t tau = (size_t)blockIdx.x * 256 + threadIdx.x;  // < 8192 (par=0)
    const int l  = (int)(tau & 63);
    const int m  = (int)((tau >> 6) & 3);
    const int ks = (int)(tau >> 8);
    const int b  = 16 * m + (l & 15);
    const int j  = ks * 32 + (l >> 4) * 8;
    const float* src = h0 + (size_t)b * HID + j;
    float f[8];
    *(float4*)&f[0] = *(const float4*)src;
    *(float4*)&f[4] = *(const float4*)(src + 4);
    s8v vh, vl;
#pragma unroll
    for (int e = 0; e < 8; ++e) {
        const unsigned short h8 = f2bf(f[e]);
        vh[e] = (short)h8;
        vl[e] = (short)f2bf(f[e] - bf2f(h8));
    }
    *(s8v*)(hi + tau * 8) = vh;
    *(s8v*)(lo + tau * 8) = vl;
}

// ---------------------------------------------------------------------------
// Per-step MFMA kernel: 256 blocks x 512 threads (8 waves).
// wave wv: m-group mg=wv>>2 (tiles 2mg,2mg+1), k-quarter kh=wv&3
// (ks in [kh*16,kh*16+16): kh<2 -> x planes, kh>=2 -> h planes).
// 3-pass split precision: acc += Ahi*Bhi + Ahi*Blo + Alo*Bhi.
// No LDS in main loop; 2 barriers for the 4-way k-reduce; v2 tail + h repack.
// ---------------------------------------------------------------------------
__global__ __launch_bounds__(512) void lstm_step_mfma(
    int t,
    const unsigned short* __restrict__ xPHi, const unsigned short* __restrict__ xPLo,
    const unsigned short* __restrict__ wPHi, const unsigned short* __restrict__ wPLo,
    const unsigned short* __restrict__ hPHi, const unsigned short* __restrict__ hPLo,
    unsigned short* __restrict__ hPHiW,      unsigned short* __restrict__ hPLoW,
    const float* __restrict__ cprev,
    const float* __restrict__ bih, const float* __restrict__ bhh,
    float* __restrict__ cbuf, float* __restrict__ out, float* __restrict__ tailp)
{
    __shared__ float part_s[8][64][8];    // 16 KB
    __shared__ float gates_s[64][17];     // 4.4 KB

    const int bid = blockIdx.x;
    const int tid = threadIdx.x;
    const int wv  = __builtin_amdgcn_readfirstlane(tid >> 6);
    const int l   = tid & 63;
    const int mg  = wv >> 2;             // 0..1
    const int kh  = wv & 3;              // 0..3
    const int par = t & 1;
    const int m0  = 2 * mg, m1 = 2 * mg + 1;

    const unsigned short *aHi, *aLo;
    if (kh < 2) {
        const size_t base = (((size_t)t * 32 + kh * 16) * 4) * 512;
        aHi = xPHi + base;  aLo = xPLo + base;
    } else {
        const size_t base = (((size_t)par * 32 + (kh - 2) * 16) * 4) * 512;
        aHi = hPHi + base;  aLo = hPLo + base;
    }
    const unsigned short* bHiP = wPHi + ((size_t)bid * 64 + kh * 16) * 512;
    const unsigned short* bLoP = wPLo + ((size_t)bid * 64 + kh * 16) * 512;

#define LDA(P, i, m) (*(const s8v*)((P) + ((size_t)(i) * 2048 + (m) * 512 + l * 8)))
#define LDB(P, i)    (*(const s8v*)((P) + ((size_t)(i) * 512 + l * 8)))

    f32x4 acc0 = {0.f, 0.f, 0.f, 0.f};
    f32x4 acc1 = {0.f, 0.f, 0.f, 0.f};

    s8v A0h = LDA(aHi, 0, m0), A0l = LDA(aLo, 0, m0);
    s8v A1h = LDA(aHi, 0, m1), A1l = LDA(aLo, 0, m1);
    s8v Bh  = LDB(bHiP, 0),    Bl  = LDB(bLoP, 0);

#pragma unroll 4
    for (int i = 0; i < 16; ++i) {
        s8v nA0h, nA0l, nA1h, nA1l, nBh, nBl;
        if (i < 15) {
            nA0h = LDA(aHi, i + 1, m0); nA0l = LDA(aLo, i + 1, m0);
            nA1h = LDA(aHi, i + 1, m1); nA1l = LDA(aLo, i + 1, m1);
            nBh  = LDB(bHiP, i + 1);    nBl  = LDB(bLoP, i + 1);
        }
        acc0 = __builtin_amdgcn_mfma_f32_16x16x32_bf16(A0h, Bh, acc0, 0, 0, 0);
        acc1 = __builtin_amdgcn_mfma_f32_16x16x32_bf16(A1h, Bh, acc1, 0, 0, 0);
        acc0 = __builtin_amdgcn_mfma_f32_16x16x32_bf16(A0h, Bl, acc0, 0, 0, 0);
        acc1 = __builtin_amdgcn_mfma_f32_16x16x32_bf16(A1h, Bl, acc1, 0, 0, 0);
        acc0 = __builtin_amdgcn_mfma_f32_16x16x32_bf16(A0l, Bh, acc0, 0, 0, 0);
        acc1 = __builtin_amdgcn_mfma_f32_16x16x32_bf16(A1l, Bh, acc1, 0, 0, 0);
        A0h = nA0h; A0l = nA0l; A1h = nA1h; A1l = nA1l; Bh = nBh; Bl = nBl;
    }
#undef LDA
#undef LDB

    // --- 4-way k-reduce through LDS (2 barriers) ---
    *(f32x4*)&part_s[wv][l][0] = acc0;
    *(f32x4*)&part_s[wv][l][4] = acc1;
    __syncthreads();
    if (tid < 128) {
        const int mg2 = tid >> 6, l2 = tid & 63;
        f32x4 s0 = {0.f, 0.f, 0.f, 0.f};
        f32x4 s1 = {0.f, 0.f, 0.f, 0.f};
#pragma unroll
        for (int k = 0; k < 4; ++k) {
            s0 += *(const f32x4*)&part_s[mg2 * 4 + k][l2][0];
            s1 += *(const f32x4*)&part_s[mg2 * 4 + k][l2][4];
        }
        const int c = l2 & 15, rb = (l2 >> 4) * 4;
#pragma unroll
        for (int r = 0; r < 4; ++r) {
            gates_s[16 * (2 * mg2 + 0) + rb + r][c] = s0[r];
            gates_s[16 * (2 * mg2 + 1) + rb + r][c] = s1[r];
        }
    }
    __syncthreads();

    // --- elementwise LSTM cell update + h repack for next step ---
    if (tid < 256) {
        const int b  = tid >> 2;
        const int jj = tid & 3;
        const int j  = bid * 4 + jj;
        const float pre_i = gates_s[b][0  + jj] + bih[0 * HID + j] + bhh[0 * HID + j];
        const float pre_f = gates_s[b][4  + jj] + bih[1 * HID + j] + bhh[1 * HID + j];
        const float pre_g = gates_s[b][8  + jj] + bih[2 * HID + j] + bhh[2 * HID + j];
        const float pre_o = gates_s[b][12 + jj] + bih[3 * HID + j] + bhh[3 * HID + j];
        const float ig = 1.0f / (1.0f + __expf(-pre_i));
        const float fg = 1.0f / (1.0f + __expf(-pre_f));
        const float gg = tanhf(pre_g);
        const float og = 1.0f / (1.0f + __expf(-pre_o));
        const float cp = cprev[b * HID + j];
        const float cn = fg * cp + ig * gg;
        const float hn = og * tanhf(cn);
        cbuf[b * HID + j] = cn;
        out[((size_t)t * BATCH + b) * HID + j] = hn;
        if (t == T_STEPS - 1) {
            tailp[b * HID + j] = hn;                              // h_T
            tailp[(size_t)BATCH * HID + b * HID + j] = cn;        // c_T
        }
        // repack hn into fragment planes, parity par^1
        const int parn = par ^ 1;
        const unsigned short hhi = f2bf(hn);
        const unsigned short hlo = f2bf(hn - bf2f(hhi));
        const size_t idx = ((((size_t)parn * 32 + (j >> 5)) * 4 + (b >> 4)) * 64
                            + ((b & 15) + 16 * ((j & 31) >> 3))) * 8 + (j & 7);
        hPHiW[idx] = hhi;
        hPLoW[idx] = hlo;
    }
}

// ---------------------------------------------------------------------------
// Fallback (proven v2): fused fp32 per-step kernel, wave-private LDS staging.
// Used when workspace is too small for the packed planes.
// ---------------------------------------------------------------------------
__global__ __launch_bounds__(512) void lstm_step_f32(
    const float* __restrict__ x, const float* __restrict__ hprev,
    const float* __restrict__ cprev,
    const float* __restrict__ Wih, const float* __restrict__ Whh,
    const float* __restrict__ bih, const float* __restrict__ bhh,
    float* __restrict__ cnext, float* __restrict__ hout,
    float* __restrict__ tail)
{
    __shared__ float h_s[8][16][68];
    __shared__ float w_s[8][16][20];
    __shared__ float gates_s[64][17];
    float* part_s = &h_s[0][0][0];

    const int bid = blockIdx.x;
    const int tid = threadIdx.x;
    const int j0  = bid * 4;
    const int wv  = tid >> 6;
    const int gl  = tid & 63;
    const int b0  = (gl >> 2) * 4;
    const int c0_ = (gl & 3) * 4;

    const float* __restrict__ src = (wv < 4) ? x   : hprev;
    const float* __restrict__ W   = (wv < 4) ? Wih : Whh;
    const int kbase = (wv & 3) * 256;

    float acc[4][4] = {};
    float4 hv[4], wvf;

#pragma unroll
    for (int r = 0; r < 4; ++r) {
        const int fidx = r * 64 + gl;
        hv[r] = *(const float4*)(src + (fidx >> 2) * DIM + kbase + (fidx & 3) * 4);
    }
    {
        const int c = gl >> 2, k4 = (gl & 3) * 4;
        const int n = (c >> 2) * HID + j0 + (c & 3);
        wvf = *(const float4*)(W + (size_t)n * DIM + kbase + k4);
    }

    for (int ci = 0; ci < 16; ++ci) {
#pragma unroll
        for (int r = 0; r < 4; ++r) {
            const int fidx = r * 64 + gl;
            const int b = fidx >> 2, k4 = (fidx & 3) * 4;
            h_s[wv][k4 + 0][b] = hv[r].x; h_s[wv][k4 + 1][b] = hv[r].y;
            h_s[wv][k4 + 2][b] = hv[r].z; h_s[wv][k4 + 3][b] = hv[r].w;
        }
        {
            const int c = gl >> 2, k4 = (gl & 3) * 4;
            w_s[wv][k4 + 0][c] = wvf.x; w_s[wv][k4 + 1][c] = wvf.y;
            w_s[wv][k4 + 2][c] = wvf.z; w_s[wv][k4 + 3][c] = wvf.w;
        }
        if (ci < 15) {
            const int kb = kbase + (ci + 1) * 16;
#pragma unroll
            for (int r = 0; r < 4; ++r) {
                const int fidx = r * 64 + gl;
                hv[r] = *(const float4*)(src + (fidx >> 2) * DIM + kb + (fidx & 3) * 4);
            }
            {
                const int c = gl >> 2, k4 = (gl & 3) * 4;
                const int n = (c >> 2) * HID + j0 + (c & 3);
                wvf = *(const float4*)(W + (size_t)n * DIM + kb + k4);
            }
        }
#pragma unroll
        for (int kk = 0; kk < 16; ++kk) {
            const float4 h4 = *(const float4*)&h_s[wv][kk][b0];
            const float4 w4 = *(const float4*)&w_s[wv][kk][c0_];
            const float hr[4] = {h4.x, h4.y, h4.z, h4.w};
            const float wr[4] = {w4.x, w4.y, w4.z, w4.w};
#pragma unroll
            for (int i = 0; i < 4; ++i)
#pragma unroll
                for (int j = 0; j < 4; ++j)
                    acc[i][j] += hr[i] * wr[j];
        }
    }

    __syncthreads();
#pragma unroll
    for (int i = 0; i < 4; ++i)
#pragma unroll
        for (int j = 0; j < 4; ++j)
            part_s[tid * 17 + i * 4 + j] = acc[i][j];
    __syncthreads();
    if (tid < 64) {
#pragma unroll
        for (int i = 0; i < 4; ++i)
#pragma unroll
            for (int j = 0; j < 4; ++j) {
                const int idx = i * 4 + j;
                float s = 0.0f;
#pragma unroll
                for (int p = 0; p < 8; ++p)
                    s += part_s[(gl + 64 * p) * 17 + idx];
                gates_s[b0 + i][c0_ + j] = s;
            }
    }
    __syncthreads();

    if (tid < 256) {
        const int b  = tid >> 2;
        const int jj = tid & 3;
        const int j  = j0 + jj;
        const float pre_i = gates_s[b][0  + jj] + bih[0 * HID + j] + bhh[0 * HID + j];
        const float pre_f = gates_s[b][4  + jj] + bih[1 * HID + j] + bhh[1 * HID + j];
        const float pre_g = gates_s[b][8  + jj] + bih[2 * HID + j] + bhh[2 * HID + j];
        const float pre_o = gates_s[b][12 + jj] + bih[3 * HID + j] + bhh[3 * HID + j];
        const float ig = 1.0f / (1.0f + __expf(-pre_i));
        const float fg = 1.0f / (1.0f + __expf(-pre_f));
        const float gg = tanhf(pre_g);
        const float og = 1.0f / (1.0f + __expf(-pre_o));
        const float cp = cprev[b * HID + j];
        const float cn = fg * cp + ig * gg;
        const float hn = og * tanhf(cn);
        cnext[b * HID + j] = cn;
        hout[b * HID + j]  = hn;
        if (tail) {
            tail[b * HID + j] = hn;
            tail[(size_t)BATCH * HID + b * HID + j] = cn;
        }
    }
}

// ---------------------------------------------------------------------------
extern "C" void kernel_launch(void* const* d_in, const int* in_sizes, int n_in,
                              void* d_out, int out_size, void* d_ws, size_t ws_size,
                              hipStream_t stream) {
    const float* inputs = (const float*)d_in[0];
    const float* h0     = (const float*)d_in[1];
    const float* c0     = (const float*)d_in[2];
    const float* W_ih   = (const float*)d_in[3];
    const float* W_hh   = (const float*)d_in[4];
    const float* b_ih   = (const float*)d_in[5];
    const float* b_hh   = (const float*)d_in[6];
    float* out = (float*)d_out;

    const size_t XP = (size_t)T_STEPS * 32 * 4 * 512;  // 33,554,432 elems/plane
    const size_t WP = (size_t)256 * 64 * 512;          //  8,388,608
    const size_t HP = (size_t)2 * 32 * 4 * 512;        //    131,072
    const size_t needB = (2 * XP + 2 * WP + 2 * HP) * sizeof(unsigned short)
                         + (size_t)BATCH * HID * sizeof(float);

    if (ws_size >= needB) {
        unsigned short* xPHi = (unsigned short*)d_ws;
        unsigned short* xPLo = xPHi + XP;
        unsigned short* wPHi = xPLo + XP;
        unsigned short* wPLo = wPHi + WP;
        unsigned short* hPHi = wPLo + WP;
        unsigned short* hPLo = hPHi + HP;
        float* cbuf = (float*)(hPLo + HP);

        pack_x<<<dim3(16384), dim3(256), 0, stream>>>(inputs, xPHi, xPLo);
        pack_w<<<dim3(4096),  dim3(256), 0, stream>>>(W_ih, W_hh, wPHi, wPLo);
        pack_h0<<<dim3(32),   dim3(256), 0, stream>>>(h0, hPHi, hPLo);

        for (int t = 0; t < T_STEPS; ++t) {
            const float* cp = (t == 0) ? c0 : cbuf;
            float* tailp = out + (size_t)T_STEPS * BATCH * HID;
            lstm_step_mfma<<<dim3(256), dim3(512), 0, stream>>>(
                t, xPHi, xPLo, wPHi, wPLo, hPHi, hPLo, hPHi, hPLo,
                cp, b_ih, b_hh, cbuf, out, tailp);
        }
    } else {
        float* cbuf = (float*)d_ws;
        for (int t = 0; t < T_STEPS; ++t) {
            const float* x  = inputs + (size_t)t * BATCH * DIM;
            const float* hp = (t == 0) ? h0 : out + (size_t)(t - 1) * BATCH * HID;
            const float* cp = (t == 0) ? c0 : cbuf;
            float* ho   = out + (size_t)t * BATCH * HID;
            float* tailp = (t == T_STEPS - 1)
                         ? out + (size_t)T_STEPS * BATCH * HID : nullptr;
            lstm_step_f32<<<dim3(256), dim3(512), 0, stream>>>(
                x, hp, cp, W_ih, W_hh, b_ih, b_hh, cbuf, ho, tailp);
        }
    }
}